// Round 20
// baseline (300.765 us; speedup 1.0000x reference)
//
#include <hip/hip_runtime.h>

typedef short short8 __attribute__((ext_vector_type(8)));
typedef float float4v __attribute__((ext_vector_type(4)));
typedef unsigned short u16;
typedef unsigned int u32;

#define T_LEN 4096
#define DDIM 512
#define BATCH 8
#define MROWS 32768
#define CH 32
#define NC 128   // T_LEN / CH

__device__ __forceinline__ u16 f2b(float x) {
    unsigned u = __float_as_uint(x);
    unsigned r = (u + 0x7FFFu + ((u >> 16) & 1u)) >> 16;
    return (u16)r;
}
__device__ __forceinline__ float b2f(u16 h) {
    return __uint_as_float((u32)h << 16);
}
__device__ __forceinline__ float sigm(float x) {
    return __builtin_amdgcn_rcpf(1.f + __builtin_amdgcn_exp2f(-1.44269504f * x));
}
__device__ __forceinline__ float tanh_fast(float x) {
    return 1.f - 2.f * __builtin_amdgcn_rcpf(1.f + __builtin_amdgcn_exp2f(2.88539008f * x));
}

__device__ __forceinline__ void gl2lds16(const u16* g, u16* l) {
    __builtin_amdgcn_global_load_lds(
        (const __attribute__((address_space(1))) void*)g,
        (__attribute__((address_space(3))) void*)l, 16, 0, 0);
}

// ordered affine compose across lh lanes (see R17)
__device__ __forceinline__ void compose_xor(float& A, float& B, int mask,
                                            bool selfIsHi) {
    float pa = __shfl_xor(A, mask);
    float pb = __shfl_xor(B, mask);
    float loA = selfIsHi ? pa : A, loB = selfIsHi ? pb : B;
    float hiA = selfIsHi ? A : pa, hiB = selfIsHi ? B : pb;
    A = hiA * loA;
    B = hiA * loB + hiB;
}

// ---------------- converts ----------------
__global__ __launch_bounds__(256) void cvt_x(const float* __restrict__ x,
                                             u16* __restrict__ xb, size_t n) {
    size_t i = ((size_t)blockIdx.x * 256 + threadIdx.x) * 4;
    if (i < n) {
        float4v v = *(const float4v*)&x[i];
        ushort4 p;
        p.x = f2b(v[0]); p.y = f2b(v[1]); p.z = f2b(v[2]); p.w = f2b(v[3]);
        *(ushort4*)&xb[i] = p;
    }
}

// merged weight transpose (all 3, gate-interleaved)
// rows: [0,1024) W_in (NG=2) | [1024,3072) W_mid (NG=4) | [3072,3584) W_out
__global__ __launch_bounds__(256) void cvt_wt_all(
    const float* __restrict__ W_in, const float* __restrict__ W_mid,
    const float* __restrict__ W_out, u16* __restrict__ wt_in,
    u16* __restrict__ wt_mid, u16* __restrict__ wt_out) {
    int idx = blockIdx.x * 256 + threadIdx.x;
    int j = idx >> 9;
    int k = idx & 511;
    if (j < 1024) {
        int gate = (j >> 4) & 1, d = (j >> 5) * 16 + (j & 15);
        wt_in[(size_t)j * 512 + k] =
            f2b(W_in[((size_t)gate * 512 + k) * 512 + d]);
    } else if (j < 3072) {
        int j2 = j - 1024;
        int gate = (j2 >> 4) & 3, d = (j2 >> 6) * 16 + (j2 & 15);
        wt_mid[(size_t)j2 * 512 + k] =
            f2b(W_mid[((size_t)gate * 512 + k) * 512 + d]);
    } else {
        int j3 = j - 3072;
        wt_out[(size_t)j3 * 512 + k] = f2b(W_out[(size_t)k * 512 + j3]);
    }
}

// ---------------- GEMM + fused gate epilogue + fused scan partials ------
// R19 verbatim (proven 239us): 8 waves, BM=256 x BN=128, 64x64 wave tile,
// BK=32, R7 chunk swizzle, 3-buffer counted vmcnt(3), XCD swizzle,
// gate-interleaved B, epilogue f/g(/o) bf16 + chunk partials (A,B) to cA/cB.
template <int MODE>  // 1 or 2 only
__global__ __launch_bounds__(512, 4) void gemm_act(
    const u16* __restrict__ A, const u16* __restrict__ Bt,
    const float* __restrict__ bias, void* __restrict__ o0v,
    void* __restrict__ o1v, void* __restrict__ o2v,
    float* __restrict__ cA, float* __restrict__ cB) {
    constexpr int K = 512;
    constexpr int BK = 32;
    constexpr int NKT = K / BK;        // 16
    constexpr int LBA = 256 * 32;
    constexpr int LBB = 128 * 32;
    constexpr int GX = (MODE == 1) ? 8 : 16;
    constexpr int NWG = 128 * GX;
    __shared__ u16 lsA[3][LBA];        // 48KB
    __shared__ u16 lsB[3][LBB];        // 24KB
    const int tid = threadIdx.x;
    const int lane = tid & 63;
    const int wid = tid >> 6;
    const int wr = wid >> 1;           // 0..3 (M quarter)
    const int wc = wid & 1;            // 0..1 (N half)
    const int l0 = lane & 15, lh = lane >> 4;

    const int h = blockIdx.x;
    const int l = (h & 7) * (NWG / 8) + (h >> 3);
    const int bn0 = (l & (GX - 1)) * 128;
    const int bm0 = (l / GX) * 256;

    float4v acc[4][4];
#pragma unroll
    for (int m = 0; m < 4; ++m)
#pragma unroll
        for (int n = 0; n < 4; ++n) acc[m][n] = (float4v){0.f, 0.f, 0.f, 0.f};

    int growA[2], gchA[2], growB, gchB;
#pragma unroll
    for (int i = 0; i < 2; ++i) {
        int flat = i * 512 + tid;
        growA[i] = flat >> 2;
        gchA[i] = (((flat & 3) ^ ((growA[i] >> 1) & 3))) * 8;
    }
    growB = tid >> 2;
    gchB = (((tid & 3) ^ ((growB >> 1) & 3))) * 8;

#define STAGE(buf, kt)                                                        \
    {                                                                         \
        const int k0 = (kt) * BK;                                             \
        _Pragma("unroll") for (int i = 0; i < 2; ++i)                         \
            gl2lds16(&A[(size_t)(bm0 + growA[i]) * K + k0 + gchA[i]],         \
                     &lsA[buf][(i * 512 + tid) * 8]);                         \
        gl2lds16(&Bt[(size_t)(bn0 + growB) * K + k0 + gchB],                  \
                 &lsB[buf][tid * 8]);                                         \
    }

    STAGE(0, 0);
    STAGE(1, 1);

    for (int kt = 0; kt < NKT; ++kt) {
        const int cur = kt % 3;
        if (kt + 1 < NKT)
            asm volatile("s_waitcnt vmcnt(3)" ::: "memory");
        else
            asm volatile("s_waitcnt vmcnt(0)" ::: "memory");
        __builtin_amdgcn_s_barrier();
        __builtin_amdgcn_sched_barrier(0);
        if (kt + 2 < NKT) STAGE((kt + 2) % 3, kt + 2);
        short8 af[4], bf[4];
#pragma unroll
        for (int m = 0; m < 4; ++m) {
            int r = wr * 64 + m * 16 + l0;
            af[m] = *(const short8*)&lsA[cur][r * 32 + ((lh ^ ((r >> 1) & 3)) * 8)];
        }
#pragma unroll
        for (int n = 0; n < 4; ++n) {
            int r = wc * 64 + n * 16 + l0;
            bf[n] = *(const short8*)&lsB[cur][r * 32 + ((lh ^ ((r >> 1) & 3)) * 8)];
        }
        asm volatile("s_waitcnt lgkmcnt(0)" ::: "memory");
        __builtin_amdgcn_sched_barrier(0);
        __builtin_amdgcn_s_setprio(1);
#pragma unroll
        for (int m = 0; m < 4; ++m)
#pragma unroll
            for (int n = 0; n < 4; ++n)
                acc[m][n] = __builtin_amdgcn_mfma_f32_16x16x32_bf16(
                    af[m], bf[n], acc[m][n], 0, 0, 0);
        __builtin_amdgcn_s_setprio(0);
    }
#undef STAGE

    const int bb = bm0 >> 12;                 // batch index
    const int tq = (bm0 & 4095) + wr * 64;    // quarter's t-base

    if (MODE == 1) {
        const int base5 = (bn0 + wc * 64) >> 5;
#pragma unroll
        for (int p = 0; p < 2; ++p) {
            const int d = (base5 + p) * 16 + l0;
            const float bvv = bias[d], bvf = bias[512 + d];
            float segA[4], segB[4];
#pragma unroll
            for (int m = 0; m < 4; ++m) {
                float Ap = 1.f, Bp = 0.f;
#pragma unroll
                for (int r = 0; r < 4; ++r) {
                    int rw = bm0 + wr * 64 + m * 16 + lh * 4 + r;
                    float f1 = sigm(acc[m][2 * p + 1][r] + bvf);
                    float g = (1.f - f1) * tanh_fast(acc[m][2 * p][r] + bvv);
                    size_t oidx = (size_t)rw * 512 + d;
                    ((u16*)o0v)[oidx] = f2b(f1);
                    ((u16*)o1v)[oidx] = f2b(g);
                    Bp = f1 * Bp + g;
                    Ap *= f1;
                }
                segA[m] = Ap; segB[m] = Bp;
            }
#pragma unroll
            for (int m = 0; m < 4; ++m) {
                compose_xor(segA[m], segB[m], 16, (lh & 1) != 0);
                compose_xor(segA[m], segB[m], 32, (lh & 2) != 0);
            }
            if (lh == 0) {
                float c0A = segA[1] * segA[0], c0B = segA[1] * segB[0] + segB[1];
                float c1A = segA[3] * segA[2], c1B = segA[3] * segB[2] + segB[3];
                int c0 = tq >> 5;
                size_t ci0 = (size_t)c0 * 4096 + bb * 512 + d;
                size_t ci1 = ci0 + 4096;
                cA[ci0] = c0A; cB[ci0] = c0B;
                cA[ci1] = c1A; cB[ci1] = c1B;
            }
        }
    } else {  // MODE 2: acc[m][0..3] = f2,i,o,z of same d
        const int d = ((bn0 + wc * 64) >> 6) * 16 + l0;
        const float bv0 = bias[d], bv1 = bias[512 + d];
        const float bv2 = bias[1024 + d], bv3 = bias[1536 + d];
        float segA[4], segB[4];
#pragma unroll
        for (int m = 0; m < 4; ++m) {
            float Ap = 1.f, Bp = 0.f;
#pragma unroll
            for (int r = 0; r < 4; ++r) {
                int rw = bm0 + wr * 64 + m * 16 + lh * 4 + r;
                float f2 = sigm(acc[m][0][r] + bv0);
                float ii = sigm(acc[m][1][r] + bv1);
                float oo = sigm(acc[m][2][r] + bv2);
                float zz = tanh_fast(acc[m][3][r] + bv3);
                float g = (1.f - f2) * ii * zz;
                size_t oidx = (size_t)rw * 512 + d;
                ((u16*)o0v)[oidx] = f2b(f2);
                ((u16*)o1v)[oidx] = f2b(g);
                ((u16*)o2v)[oidx] = f2b(oo);
                Bp = f2 * Bp + g;
                Ap *= f2;
            }
            segA[m] = Ap; segB[m] = Bp;
        }
#pragma unroll
        for (int m = 0; m < 4; ++m) {
            compose_xor(segA[m], segB[m], 16, (lh & 1) != 0);
            compose_xor(segA[m], segB[m], 32, (lh & 2) != 0);
        }
        if (lh == 0) {
            float c0A = segA[1] * segA[0], c0B = segA[1] * segB[0] + segB[1];
            float c1A = segA[3] * segA[2], c1B = segA[3] * segB[2] + segB[3];
            int c0 = tq >> 5;
            size_t ci0 = (size_t)c0 * 4096 + bb * 512 + d;
            size_t ci1 = ci0 + 4096;
            cA[ci0] = c0A; cB[ci0] = c0B;
            cA[ci1] = c1A; cB[ci1] = c1B;
        }
    }
}

// ---------------- scan1 pass3, with fused carry prefix (p2 removed) -----
// Each block computes its own carry-in from RAW chunk partials (cA/cB are
// 2MB, L2-resident; <=127 fma-chain iters with independent float4 loads).
__global__ __launch_bounds__(128) void scan_p3_1(
    const u16* __restrict__ f, const u16* __restrict__ g,
    const float* __restrict__ cA, const float* __restrict__ cB,
    u16* __restrict__ hb, float* __restrict__ hid) {
    int d0 = threadIdx.x * 4;
    int c = blockIdx.x & (NC - 1);
    int b = blockIdx.x >> 7;
    // prefix over chunks 0..c-1
    float h[4] = {0.f, 0.f, 0.f, 0.f};
    for (int cp = 0; cp < c; ++cp) {
        size_t ix = (size_t)cp * 4096 + b * DDIM + d0;
        float4v a = *(const float4v*)&cA[ix];
        float4v bb = *(const float4v*)&cB[ix];
#pragma unroll
        for (int j = 0; j < 4; ++j) h[j] = a[j] * h[j] + bb[j];
    }
    size_t base = ((size_t)b * T_LEN + c * CH) * DDIM + d0;
    for (int t = 0; t < CH; ++t) {
        ushort4 fq = *(const ushort4*)&f[base];
        ushort4 gq = *(const ushort4*)&g[base];
        float ff[4] = {b2f(fq.x), b2f(fq.y), b2f(fq.z), b2f(fq.w)};
        float gg[4] = {b2f(gq.x), b2f(gq.y), b2f(gq.z), b2f(gq.w)};
#pragma unroll
        for (int j = 0; j < 4; ++j) h[j] = ff[j] * h[j] + gg[j];
        ushort4 p;
        p.x = f2b(h[0]); p.y = f2b(h[1]); p.z = f2b(h[2]); p.w = f2b(h[3]);
        *(ushort4*)&hb[base] = p;
        base += DDIM;
    }
    if (c == NC - 1) {
#pragma unroll
        for (int j = 0; j < 4; ++j) hid[b * 1024 + d0 + j] = h[j];
    }
}

// ---------------- fused scan2-p3 + GEMM3 ----------------
// Block = (b, c2): 64 t-rows (chunks 2c2, 2c2+1), 256 threads (4 waves).
// Phase 1: per-thread carry prefix from raw partials (p2 fused).
// Phase 2: scan 32 t-steps; s = h*o -> bf16 into 64KB swizzled LDS tile
//   (chunk64 cd' = cd ^ (row&7): 2-way banks on b128 reads); hid at end.
// Phase 3: out[64 x 512] = s @ W_out + b_out. A-frags from LDS; B-frags
//   loaded DIRECTLY from wt_out (global, L2-resident; 4 lanes/64B line =
//   coalesced). Wave w = 128-col quarter; acc[4][8] (AGPRs); bf double-
//   buffered across k-steps to hide L2 latency.
__global__ __launch_bounds__(256) void scan_gemm3(
    const u16* __restrict__ f, const u16* __restrict__ g,
    const u16* __restrict__ o, const float* __restrict__ cA,
    const float* __restrict__ cB, const u16* __restrict__ Wt,
    const float* __restrict__ bias, float* __restrict__ out,
    float* __restrict__ hid) {
    __shared__ u16 lds_s[64 * 512];  // 64KB
    const int tid = threadIdx.x;

    // XCD swizzle (512 blocks)
    const int hh = blockIdx.x;
    const int lg = (hh & 7) * 64 + (hh >> 3);
    const int b = lg >> 6, c2 = lg & 63;

    // ---- phase 1+2: scan ----
    {
        const int ccl = tid >> 7;            // 0/1
        const int d0 = (tid & 127) * 4;
        const int cc = c2 * 2 + ccl;
        float h[4] = {0.f, 0.f, 0.f, 0.f};
        for (int cp = 0; cp < cc; ++cp) {
            size_t ix = (size_t)cp * 4096 + b * DDIM + d0;
            float4v a = *(const float4v*)&cA[ix];
            float4v bb = *(const float4v*)&cB[ix];
#pragma unroll
            for (int j = 0; j < 4; ++j) h[j] = a[j] * h[j] + bb[j];
        }
        size_t base = ((size_t)b * T_LEN + cc * CH) * DDIM + d0;
        const int cd = d0 >> 3, dlo = d0 & 7;
        for (int t = 0; t < CH; ++t) {
            ushort4 fq = *(const ushort4*)&f[base];
            ushort4 gq = *(const ushort4*)&g[base];
            ushort4 oq = *(const ushort4*)&o[base];
            float ff[4] = {b2f(fq.x), b2f(fq.y), b2f(fq.z), b2f(fq.w)};
            float gg[4] = {b2f(gq.x), b2f(gq.y), b2f(gq.z), b2f(gq.w)};
            float oo[4] = {b2f(oq.x), b2f(oq.y), b2f(oq.z), b2f(oq.w)};
            float w[4];
#pragma unroll
            for (int j = 0; j < 4; ++j) {
                h[j] = ff[j] * h[j] + gg[j];
                w[j] = h[j] * oo[j];
            }
            int row = ccl * 32 + t;
            ushort4 p;
            p.x = f2b(w[0]); p.y = f2b(w[1]); p.z = f2b(w[2]); p.w = f2b(w[3]);
            *(ushort4*)&lds_s[row * 512 + ((cd ^ (row & 7)) << 3) + dlo] = p;
            base += DDIM;
        }
        if (cc == NC - 1) {
#pragma unroll
            for (int j = 0; j < 4; ++j) hid[b * 1024 + 512 + d0 + j] = h[j];
        }
    }
    __syncthreads();

    // ---- phase 3: out[64 rows] = s @ W_out + b_out ----
    const int lane = tid & 63;
    const int wid = tid >> 6;           // 0..3: 128-col quarter
    const int l0 = lane & 15, lh = lane >> 4;

    float4v acc[4][8];
#pragma unroll
    for (int m = 0; m < 4; ++m)
#pragma unroll
        for (int n = 0; n < 8; ++n) acc[m][n] = (float4v){0.f, 0.f, 0.f, 0.f};

    // B-frag pointers: col = wid*128 + n*16 + l0; k-offset = ks*32 + lh*8
    const u16* wbase = &Wt[(size_t)(wid * 128 + l0) * 512 + lh * 8];

    short8 bfc[8], bfn[8];
#pragma unroll
    for (int n = 0; n < 8; ++n)
        bfc[n] = *(const short8*)&wbase[(size_t)n * 16 * 512];

    for (int ks = 0; ks < 16; ++ks) {
        if (ks < 15) {
#pragma unroll
            for (int n = 0; n < 8; ++n)
                bfn[n] = *(const short8*)&wbase[(size_t)n * 16 * 512 +
                                                (ks + 1) * 32];
        }
        short8 af[4];
#pragma unroll
        for (int m = 0; m < 4; ++m) {
            int row = m * 16 + l0;
            int cd = (ks * 4 + lh) ^ (row & 7);
            af[m] = *(const short8*)&lds_s[row * 512 + cd * 8];
        }
#pragma unroll
        for (int m = 0; m < 4; ++m)
#pragma unroll
            for (int n = 0; n < 8; ++n)
                acc[m][n] = __builtin_amdgcn_mfma_f32_16x16x32_bf16(
                    af[m], bfc[n], acc[m][n], 0, 0, 0);
#pragma unroll
        for (int n = 0; n < 8; ++n) bfc[n] = bfn[n];
    }

    const size_t rbase = (size_t)b * T_LEN + c2 * 64;
#pragma unroll
    for (int m = 0; m < 4; ++m) {
#pragma unroll
        for (int n = 0; n < 8; ++n) {
            int col = wid * 128 + n * 16 + l0;
            float bv = bias[col];
#pragma unroll
            for (int r = 0; r < 4; ++r) {
                size_t rw = rbase + m * 16 + lh * 4 + r;
                out[rw * 512 + col] = acc[m][n][r] + bv;
            }
        }
    }
}

// ---------------- launch ----------------
extern "C" void kernel_launch(void* const* d_in, const int* in_sizes, int n_in,
                              void* d_out, int out_size, void* d_ws,
                              size_t ws_size, hipStream_t stream) {
    const float* x = (const float*)d_in[0];
    const float* W_in = (const float*)d_in[1];
    const float* b_in = (const float*)d_in[2];
    const float* W_mid = (const float*)d_in[3];
    const float* b_mid = (const float*)d_in[4];
    const float* W_out = (const float*)d_in[5];
    const float* b_out = (const float*)d_in[6];
    float* out = (float*)d_out;
    char* ws = (char*)d_ws;

    const size_t MB = 1u << 20;
    const size_t MD = (size_t)MROWS * DDIM;  // 16.7M elems

    u16* wt_in = (u16*)(ws);              // 1 MB
    u16* wt_mid = (u16*)(ws + 1 * MB);    // 2 MB
    u16* wt_out = (u16*)(ws + 3 * MB);    // 0.5 MB
    u16* hb = (u16*)(ws + 4 * MB);        // 32 MB (xb -> h1)
    u16* S0 = (u16*)(ws + 36 * MB);       // 32 MB (f stream)
    u16* S1 = (u16*)(ws + 68 * MB);       // 32 MB (g stream)
    u16* S2 = (u16*)(ws + 100 * MB);      // 32 MB (o stream)
    float* cA = (float*)(ws + 164 * MB);  // 2 MB
    float* cB = (float*)(ws + 166 * MB);  // 2 MB
    float* hid = out + MD;

    cvt_x<<<(int)(MD / 4 / 256), 256, 0, stream>>>(x, hb, MD);
    cvt_wt_all<<<7168, 256, 0, stream>>>(W_in, W_mid, W_out, wt_in, wt_mid,
                                         wt_out);

    // GEMM1: f1(S0), g1(S1) + chunk partials
    gemm_act<1><<<1024, 512, 0, stream>>>(hb, wt_in, b_in, S0, S1, nullptr,
                                          cA, cB);
    // scan1 (prefix fused): h1 -> hb bf16; hidden_pre
    scan_p3_1<<<1024, 128, 0, stream>>>(S0, S1, cA, cB, hb, hid);

    // GEMM2: f2(S0), g(S1), o(S2) + chunk partials
    gemm_act<2><<<2048, 512, 0, stream>>>(hb, wt_mid, b_mid, S0, S1, S2,
                                          cA, cB);
    // fused scan2 + GEMM3: out = (scan(f2,g)*o) @ W_out + b_out; hidden_mid
    scan_gemm3<<<512, 256, 0, stream>>>(S0, S1, S2, cA, cB, wt_out, b_out,
                                        out, hid);
}

// Round 21
// 234.807 us; speedup vs baseline: 1.2809x; 1.2809x over previous
//
#include <hip/hip_runtime.h>

typedef short short8 __attribute__((ext_vector_type(8)));
typedef float float4v __attribute__((ext_vector_type(4)));
typedef unsigned short u16;
typedef unsigned int u32;

#define T_LEN 4096
#define DDIM 512
#define BATCH 8
#define MROWS 32768
#define CH 32
#define NC 128   // T_LEN / CH

__device__ __forceinline__ u16 f2b(float x) {
    unsigned u = __float_as_uint(x);
    unsigned r = (u + 0x7FFFu + ((u >> 16) & 1u)) >> 16;
    return (u16)r;
}
__device__ __forceinline__ float b2f(u16 h) {
    return __uint_as_float((u32)h << 16);
}
__device__ __forceinline__ float sigm(float x) {
    return __builtin_amdgcn_rcpf(1.f + __builtin_amdgcn_exp2f(-1.44269504f * x));
}
__device__ __forceinline__ float tanh_fast(float x) {
    return 1.f - 2.f * __builtin_amdgcn_rcpf(1.f + __builtin_amdgcn_exp2f(2.88539008f * x));
}

__device__ __forceinline__ void gl2lds16(const u16* g, u16* l) {
    __builtin_amdgcn_global_load_lds(
        (const __attribute__((address_space(1))) void*)g,
        (__attribute__((address_space(3))) void*)l, 16, 0, 0);
}

// ordered affine compose across lh lanes (see R17)
__device__ __forceinline__ void compose_xor(float& A, float& B, int mask,
                                            bool selfIsHi) {
    float pa = __shfl_xor(A, mask);
    float pb = __shfl_xor(B, mask);
    float loA = selfIsHi ? pa : A, loB = selfIsHi ? pb : B;
    float hiA = selfIsHi ? A : pa, hiB = selfIsHi ? B : pb;
    A = hiA * loA;
    B = hiA * loB + hiB;
}

// ---------------- merged converts (x + all 3 weights, one launch) -------
// blocks [0, 16384): cvt x (4 f32/thread)
// blocks [16384, 23552): weight transpose, gate-interleaved
__global__ __launch_bounds__(256) void cvt_all(
    const float* __restrict__ x, u16* __restrict__ xb,
    const float* __restrict__ W_in, const float* __restrict__ W_mid,
    const float* __restrict__ W_out, u16* __restrict__ wt_in,
    u16* __restrict__ wt_mid, u16* __restrict__ wt_out) {
    if (blockIdx.x < 16384) {
        size_t i = ((size_t)blockIdx.x * 256 + threadIdx.x) * 4;
        float4v v = *(const float4v*)&x[i];
        ushort4 p;
        p.x = f2b(v[0]); p.y = f2b(v[1]); p.z = f2b(v[2]); p.w = f2b(v[3]);
        *(ushort4*)&xb[i] = p;
        return;
    }
    int idx = (blockIdx.x - 16384) * 256 + threadIdx.x;
    int j = idx >> 9;
    int k = idx & 511;
    if (j < 1024) {
        int gate = (j >> 4) & 1, d = (j >> 5) * 16 + (j & 15);
        wt_in[(size_t)j * 512 + k] =
            f2b(W_in[((size_t)gate * 512 + k) * 512 + d]);
    } else if (j < 3072) {
        int j2 = j - 1024;
        int gate = (j2 >> 4) & 3, d = (j2 >> 6) * 16 + (j2 & 15);
        wt_mid[(size_t)j2 * 512 + k] =
            f2b(W_mid[((size_t)gate * 512 + k) * 512 + d]);
    } else {
        int j3 = j - 3072;
        wt_out[(size_t)j3 * 512 + k] = f2b(W_out[(size_t)k * 512 + j3]);
    }
}

// ---------------- GEMM + fused gate epilogue + fused scan partials ------
// R19 verbatim (proven 239us): 8 waves, BM=256 x BN=128, 64x64 wave tile,
// BK=32, R7 chunk swizzle (0 conflicts), 3-buffer counted vmcnt(3), XCD
// swizzle, gate-interleaved B, epilogue f/g(/o) bf16 + chunk partials.
// R20 lesson: fusing scan+GEMM3 into one kernel serializes phases with
// mismatched parallelism (occupancy 9.9%, 97us) -- keep phases split.
template <int MODE>
__global__ __launch_bounds__(512, 4) void gemm_act(
    const u16* __restrict__ A, const u16* __restrict__ Bt,
    const float* __restrict__ bias, void* __restrict__ o0v,
    void* __restrict__ o1v, void* __restrict__ o2v,
    float* __restrict__ cA, float* __restrict__ cB) {
    constexpr int K = 512;
    constexpr int BK = 32;
    constexpr int NKT = K / BK;        // 16
    constexpr int LBA = 256 * 32;
    constexpr int LBB = 128 * 32;
    constexpr int GX = (MODE == 1) ? 8 : (MODE == 2) ? 16 : 4;
    constexpr int NWG = 128 * GX;
    __shared__ u16 lsA[3][LBA];        // 48KB
    __shared__ u16 lsB[3][LBB];        // 24KB
    const int tid = threadIdx.x;
    const int lane = tid & 63;
    const int wid = tid >> 6;
    const int wr = wid >> 1;           // 0..3 (M quarter)
    const int wc = wid & 1;            // 0..1 (N half)
    const int l0 = lane & 15, lh = lane >> 4;

    const int h = blockIdx.x;
    const int l = (h & 7) * (NWG / 8) + (h >> 3);
    const int bn0 = (l & (GX - 1)) * 128;
    const int bm0 = (l / GX) * 256;

    float4v acc[4][4];
#pragma unroll
    for (int m = 0; m < 4; ++m)
#pragma unroll
        for (int n = 0; n < 4; ++n) acc[m][n] = (float4v){0.f, 0.f, 0.f, 0.f};

    int growA[2], gchA[2], growB, gchB;
#pragma unroll
    for (int i = 0; i < 2; ++i) {
        int flat = i * 512 + tid;
        growA[i] = flat >> 2;
        gchA[i] = (((flat & 3) ^ ((growA[i] >> 1) & 3))) * 8;
    }
    growB = tid >> 2;
    gchB = (((tid & 3) ^ ((growB >> 1) & 3))) * 8;

#define STAGE(buf, kt)                                                        \
    {                                                                         \
        const int k0 = (kt) * BK;                                             \
        _Pragma("unroll") for (int i = 0; i < 2; ++i)                         \
            gl2lds16(&A[(size_t)(bm0 + growA[i]) * K + k0 + gchA[i]],         \
                     &lsA[buf][(i * 512 + tid) * 8]);                         \
        gl2lds16(&Bt[(size_t)(bn0 + growB) * K + k0 + gchB],                  \
                 &lsB[buf][tid * 8]);                                         \
    }

    STAGE(0, 0);
    STAGE(1, 1);

    for (int kt = 0; kt < NKT; ++kt) {
        const int cur = kt % 3;
        if (kt + 1 < NKT)
            asm volatile("s_waitcnt vmcnt(3)" ::: "memory");
        else
            asm volatile("s_waitcnt vmcnt(0)" ::: "memory");
        __builtin_amdgcn_s_barrier();
        __builtin_amdgcn_sched_barrier(0);
        if (kt + 2 < NKT) STAGE((kt + 2) % 3, kt + 2);
        short8 af[4], bf[4];
#pragma unroll
        for (int m = 0; m < 4; ++m) {
            int r = wr * 64 + m * 16 + l0;
            af[m] = *(const short8*)&lsA[cur][r * 32 + ((lh ^ ((r >> 1) & 3)) * 8)];
        }
#pragma unroll
        for (int n = 0; n < 4; ++n) {
            int r = wc * 64 + n * 16 + l0;
            bf[n] = *(const short8*)&lsB[cur][r * 32 + ((lh ^ ((r >> 1) & 3)) * 8)];
        }
        asm volatile("s_waitcnt lgkmcnt(0)" ::: "memory");
        __builtin_amdgcn_sched_barrier(0);
        __builtin_amdgcn_s_setprio(1);
#pragma unroll
        for (int m = 0; m < 4; ++m)
#pragma unroll
            for (int n = 0; n < 4; ++n)
                acc[m][n] = __builtin_amdgcn_mfma_f32_16x16x32_bf16(
                    af[m], bf[n], acc[m][n], 0, 0, 0);
        __builtin_amdgcn_s_setprio(0);
    }
#undef STAGE

    if (MODE == 3) {
#pragma unroll
        for (int m = 0; m < 4; ++m) {
#pragma unroll
            for (int n = 0; n < 4; ++n) {
                int col = bn0 + wc * 64 + n * 16 + l0;
                float bv = bias[col];
#pragma unroll
                for (int r = 0; r < 4; ++r) {
                    int rw = bm0 + wr * 64 + m * 16 + lh * 4 + r;
                    ((float*)o0v)[(size_t)rw * 512 + col] = acc[m][n][r] + bv;
                }
            }
        }
        return;
    }

    const int bb = bm0 >> 12;                 // batch index
    const int tq = (bm0 & 4095) + wr * 64;    // quarter's t-base

    if (MODE == 1) {
        const int base5 = (bn0 + wc * 64) >> 5;
#pragma unroll
        for (int p = 0; p < 2; ++p) {
            const int d = (base5 + p) * 16 + l0;
            const float bvv = bias[d], bvf = bias[512 + d];
            float segA[4], segB[4];
#pragma unroll
            for (int m = 0; m < 4; ++m) {
                float Ap = 1.f, Bp = 0.f;
#pragma unroll
                for (int r = 0; r < 4; ++r) {
                    int rw = bm0 + wr * 64 + m * 16 + lh * 4 + r;
                    float f1 = sigm(acc[m][2 * p + 1][r] + bvf);
                    float g = (1.f - f1) * tanh_fast(acc[m][2 * p][r] + bvv);
                    size_t oidx = (size_t)rw * 512 + d;
                    ((u16*)o0v)[oidx] = f2b(f1);
                    ((u16*)o1v)[oidx] = f2b(g);
                    Bp = f1 * Bp + g;
                    Ap *= f1;
                }
                segA[m] = Ap; segB[m] = Bp;
            }
#pragma unroll
            for (int m = 0; m < 4; ++m) {
                compose_xor(segA[m], segB[m], 16, (lh & 1) != 0);
                compose_xor(segA[m], segB[m], 32, (lh & 2) != 0);
            }
            if (lh == 0) {
                float c0A = segA[1] * segA[0], c0B = segA[1] * segB[0] + segB[1];
                float c1A = segA[3] * segA[2], c1B = segA[3] * segB[2] + segB[3];
                int c0 = tq >> 5;
                size_t ci0 = (size_t)c0 * 4096 + bb * 512 + d;
                size_t ci1 = ci0 + 4096;
                cA[ci0] = c0A; cB[ci0] = c0B;
                cA[ci1] = c1A; cB[ci1] = c1B;
            }
        }
    } else {  // MODE 2: acc[m][0..3] = f2,i,o,z of same d
        const int d = ((bn0 + wc * 64) >> 6) * 16 + l0;
        const float bv0 = bias[d], bv1 = bias[512 + d];
        const float bv2 = bias[1024 + d], bv3 = bias[1536 + d];
        float segA[4], segB[4];
#pragma unroll
        for (int m = 0; m < 4; ++m) {
            float Ap = 1.f, Bp = 0.f;
#pragma unroll
            for (int r = 0; r < 4; ++r) {
                int rw = bm0 + wr * 64 + m * 16 + lh * 4 + r;
                float f2 = sigm(acc[m][0][r] + bv0);
                float ii = sigm(acc[m][1][r] + bv1);
                float oo = sigm(acc[m][2][r] + bv2);
                float zz = tanh_fast(acc[m][3][r] + bv3);
                float g = (1.f - f2) * ii * zz;
                size_t oidx = (size_t)rw * 512 + d;
                ((u16*)o0v)[oidx] = f2b(f2);
                ((u16*)o1v)[oidx] = f2b(g);
                ((u16*)o2v)[oidx] = f2b(oo);
                Bp = f2 * Bp + g;
                Ap *= f2;
            }
            segA[m] = Ap; segB[m] = Bp;
        }
#pragma unroll
        for (int m = 0; m < 4; ++m) {
            compose_xor(segA[m], segB[m], 16, (lh & 1) != 0);
            compose_xor(segA[m], segB[m], 32, (lh & 2) != 0);
        }
        if (lh == 0) {
            float c0A = segA[1] * segA[0], c0B = segA[1] * segB[0] + segB[1];
            float c1A = segA[3] * segA[2], c1B = segA[3] * segB[2] + segB[3];
            int c0 = tq >> 5;
            size_t ci0 = (size_t)c0 * 4096 + bb * 512 + d;
            size_t ci1 = ci0 + 4096;
            cA[ci0] = c0A; cB[ci0] = c0B;
            cA[ci1] = c1A; cB[ci1] = c1B;
        }
    }
}

// ---------------- scan pass 2 + 3 ----------------
__global__ __launch_bounds__(256) void scan_p2(float* __restrict__ cA,
                                               const float* __restrict__ cB) {
    int ln = blockIdx.x * 256 + threadIdx.x;  // 0..4095 = b*512+d
    float h = 0.f;
    for (int c = 0; c < NC; ++c) {
        size_t ix = (size_t)c * 4096 + ln;
        float a = cA[ix], bb = cB[ix];
        cA[ix] = h;  // exclusive carry-in
        h = a * h + bb;
    }
}

template <int S>  // S==2: multiply by o before store; hid offset
__global__ __launch_bounds__(128) void scan_p3(
    const u16* __restrict__ f, const u16* __restrict__ g,
    const u16* __restrict__ o, const float* __restrict__ cA,
    u16* __restrict__ hb, float* __restrict__ hid) {
    int d0 = threadIdx.x * 4;
    int c = blockIdx.x & (NC - 1);
    int b = blockIdx.x >> 7;
    size_t base = ((size_t)b * T_LEN + c * CH) * DDIM + d0;
    size_t ci = (size_t)c * 4096 + b * DDIM + d0;
    float h[4] = {cA[ci], cA[ci + 1], cA[ci + 2], cA[ci + 3]};
    for (int t = 0; t < CH; ++t) {
        ushort4 fq = *(const ushort4*)&f[base];
        ushort4 gq = *(const ushort4*)&g[base];
        float ff[4] = {b2f(fq.x), b2f(fq.y), b2f(fq.z), b2f(fq.w)};
        float gg[4] = {b2f(gq.x), b2f(gq.y), b2f(gq.z), b2f(gq.w)};
        float w[4];
#pragma unroll
        for (int j = 0; j < 4; ++j) {
            h[j] = ff[j] * h[j] + gg[j];
            w[j] = h[j];
        }
        if (S == 2) {
            ushort4 oq = *(const ushort4*)&o[base];
            w[0] *= b2f(oq.x); w[1] *= b2f(oq.y);
            w[2] *= b2f(oq.z); w[3] *= b2f(oq.w);
        }
        ushort4 p;
        p.x = f2b(w[0]); p.y = f2b(w[1]); p.z = f2b(w[2]); p.w = f2b(w[3]);
        *(ushort4*)&hb[base] = p;
        base += DDIM;
    }
    if (c == NC - 1) {
#pragma unroll
        for (int j = 0; j < 4; ++j)
            hid[b * 1024 + (S == 1 ? 0 : 512) + d0 + j] = h[j];
    }
}

// ---------------- launch ----------------
extern "C" void kernel_launch(void* const* d_in, const int* in_sizes, int n_in,
                              void* d_out, int out_size, void* d_ws,
                              size_t ws_size, hipStream_t stream) {
    const float* x = (const float*)d_in[0];
    const float* W_in = (const float*)d_in[1];
    const float* b_in = (const float*)d_in[2];
    const float* W_mid = (const float*)d_in[3];
    const float* b_mid = (const float*)d_in[4];
    const float* W_out = (const float*)d_in[5];
    const float* b_out = (const float*)d_in[6];
    float* out = (float*)d_out;
    char* ws = (char*)d_ws;

    const size_t MB = 1u << 20;
    const size_t MD = (size_t)MROWS * DDIM;  // 16.7M elems

    u16* wt_in = (u16*)(ws);              // 1 MB
    u16* wt_mid = (u16*)(ws + 1 * MB);    // 2 MB
    u16* wt_out = (u16*)(ws + 3 * MB);    // 0.5 MB
    u16* hb = (u16*)(ws + 4 * MB);        // 32 MB (xb -> h1 -> s)
    u16* S0 = (u16*)(ws + 36 * MB);       // 32 MB (f stream)
    u16* S1 = (u16*)(ws + 68 * MB);       // 32 MB (g stream)
    u16* S2 = (u16*)(ws + 100 * MB);      // 32 MB (o stream)
    float* cA = (float*)(ws + 164 * MB);  // 2 MB
    float* cB = (float*)(ws + 166 * MB);  // 2 MB
    float* hid = out + MD;

    // merged converts: x -> bf16 (16384 blocks) + weights (7168 blocks)
    cvt_all<<<23552, 256, 0, stream>>>(x, hb, W_in, W_mid, W_out, wt_in,
                                       wt_mid, wt_out);

    // GEMM1: f1(S0), g1(S1) + chunk partials (128 Mblk x 8 Nblk = 1024)
    gemm_act<1><<<1024, 512, 0, stream>>>(hb, wt_in, b_in, S0, S1, nullptr,
                                          cA, cB);
    // scan1: carries, then h1 -> hb bf16; hidden_pre
    scan_p2<<<16, 256, 0, stream>>>(cA, cB);
    scan_p3<1><<<1024, 128, 0, stream>>>(S0, S1, nullptr, cA, hb, hid);

    // GEMM2: f2(S0), g(S1), o(S2) + chunk partials (128 x 16 = 2048)
    gemm_act<2><<<2048, 512, 0, stream>>>(hb, wt_mid, b_mid, S0, S1, S2,
                                          cA, cB);
    // scan2: carries, then h2*o -> hb bf16; hidden_middle
    scan_p2<<<16, 256, 0, stream>>>(cA, cB);
    scan_p3<2><<<1024, 128, 0, stream>>>(S0, S1, S2, cA, hb, hid);

    // GEMM3: out = s@W_out + b_out (f32)  (128 x 4 = 512)
    gemm_act<3><<<512, 512, 0, stream>>>(hb, wt_out, b_out, out, nullptr,
                                         nullptr, nullptr, nullptr);
}